// Round 1
// baseline (439.722 us; speedup 1.0000x reference)
//
#include <hip/hip_runtime.h>
#include <math.h>

#define N_COL 512
#define ALPHA 0.1f

// ---------------------------------------------------------------------------
// Kernel 1: Condat 1-D TV prox, one thread per row.
// Faithful port of the reference flat state machine (cases A,B,C,D,E,F),
// using NaN-sentinel markers + sequential forward-fill to replicate the
// reference's seg/start + cummax fill semantics exactly (handles the
// out-of-order-k0 corner cases the same way).
// ---------------------------------------------------------------------------
__global__ __launch_bounds__(64) void tv_kernel(const float* __restrict__ x,
                                                float* __restrict__ z,
                                                int nrows) {
  const int n = N_COL;
  const float lam = ALPHA;
  int row = blockIdx.x * 64 + threadIdx.x;
  if (row >= nrows) return;
  const float* w = x + (size_t)row * n;
  float* zr = z + (size_t)row * n;

  const float NANF = __uint_as_float(0x7fc00000u);
  for (int i = 0; i < n; ++i) zr[i] = NANF;

  int k = 0, k0 = 0, km = 0, kp = 0;
  float w0 = w[0];
  float vmin = w0 - lam, vmax = w0 + lam, umin = lam, umax = -lam;
  int it = 0;
  const int max_iter = 40 * n;
  bool done = false;

  while (!done && it < max_iter) {
    ++it;
    if (k >= n - 1) {
      // ---- terminal cases ----
      if (umin < 0.f) {                     // A: flush vmin segment
        if (k0 < n) zr[k0] = vmin;
        int k0n = km + 1;
        int c = k0n; if (c < 0) c = 0; if (c > n - 1) c = n - 1;
        float wk0 = w[c];
        umax = wk0 + lam - vmax;            // uses OLD vmax
        vmin = wk0;
        umin = lam;
        k = k0n; k0 = k0n; km = k0n;        // kp unchanged
      } else if (umax > 0.f) {              // B: flush vmax segment
        if (k0 < n) zr[k0] = vmax;
        int k0n = kp + 1;
        int c = k0n; if (c < 0) c = 0; if (c > n - 1) c = n - 1;
        float wk0 = w[c];
        umin = wk0 - lam - vmin;            // uses OLD vmin
        vmax = wk0;
        umax = -lam;
        k = k0n; k0 = k0n; kp = k0n;        // km unchanged
      } else {                              // C: final segment -> done
        float fv = vmin + umin / (float)(k - k0 + 1);
        if (k0 < n) zr[k0] = fv;
        done = true;
      }
    } else {
      float wk1 = w[k + 1];
      float umin1 = umin + wk1 - vmin;
      float umax1 = umax + wk1 - vmax;
      if (umin1 < -lam) {                   // D: negative jump, flush vmin
        if (k0 < n) zr[k0] = vmin;
        int k0n = km + 1;                   // <= n-1 here
        float wk0 = w[k0n > n - 1 ? n - 1 : k0n];
        vmin = wk0;
        vmax = wk0 + 2.f * lam;
        umin = lam;
        umax = -lam;
        k = k0n; k0 = k0n; km = k0n; kp = k0n;
      } else if (umax1 > lam) {             // E: positive jump, flush vmax
        if (k0 < n) zr[k0] = vmax;
        int k0n = kp + 1;                   // <= n-1 here
        float wk0 = w[k0n > n - 1 ? n - 1 : k0n];
        vmax = wk0;
        vmin = wk0 - 2.f * lam;
        umin = lam;
        umax = -lam;
        k = k0n; k0 = k0n; km = k0n; kp = k0n;
      } else {                              // F: advance k
        int kF = k + 1;
        float denF = (float)(kF - k0 + 1);
        if (umin1 >= lam) {                 // g1
          vmin = vmin + (umin1 - lam) / denF;
          umin = lam;
          km = kF;
        } else {
          umin = umin1;
        }
        if (umax1 <= -lam) {                // g2
          vmax = vmax + (umax1 + lam) / denF;
          umax = -lam;
          kp = kF;
        } else {
          umax = umax1;
        }
        k = kF;
      }
    }
  }

  // forward fill from marker positions (index 0 is always a marker)
  float cur = 0.f;
  for (int i = 0; i < n; ++i) {
    float v = zr[i];
    if (!(v != v)) cur = v;                 // non-NaN -> new segment value
    zr[i] = cur;
  }
}

// ---------------------------------------------------------------------------
// Kernel 2: sparsemax, one wave (64 lanes) per row, 8 elements/lane in regs.
// tau found by Newton on f(tau) = sum(relu(z - tau)) - 1 (convex, piecewise
// linear, monotone convergence from tau0 = max - 1; exact in a few steps).
// In-place on z.
// ---------------------------------------------------------------------------
__global__ __launch_bounds__(256) void sparsemax_kernel(float* __restrict__ z,
                                                        int nrows) {
  const int n = N_COL;
  int wave = threadIdx.x >> 6;
  int lane = threadIdx.x & 63;
  int row = blockIdx.x * 4 + wave;
  if (row >= nrows) return;
  float* zr = z + (size_t)row * n;

  float4 a = ((const float4*)zr)[lane];
  float4 b = ((const float4*)zr)[lane + 64];
  float v0 = a.x, v1 = a.y, v2 = a.z, v3 = a.w;
  float v4 = b.x, v5 = b.y, v6 = b.z, v7 = b.w;

  // row max
  float m = fmaxf(fmaxf(fmaxf(v0, v1), fmaxf(v2, v3)),
                  fmaxf(fmaxf(v4, v5), fmaxf(v6, v7)));
#pragma unroll
  for (int s = 1; s < 64; s <<= 1) m = fmaxf(m, __shfl_xor(m, s));

  float tau = m - 1.0f;
  for (int iter = 0; iter < 64; ++iter) {
    float s = 0.f, c = 0.f;
    {
      float d;
      d = v0 - tau; if (d > 0.f) { s += d; c += 1.f; }
      d = v1 - tau; if (d > 0.f) { s += d; c += 1.f; }
      d = v2 - tau; if (d > 0.f) { s += d; c += 1.f; }
      d = v3 - tau; if (d > 0.f) { s += d; c += 1.f; }
      d = v4 - tau; if (d > 0.f) { s += d; c += 1.f; }
      d = v5 - tau; if (d > 0.f) { s += d; c += 1.f; }
      d = v6 - tau; if (d > 0.f) { s += d; c += 1.f; }
      d = v7 - tau; if (d > 0.f) { s += d; c += 1.f; }
    }
#pragma unroll
    for (int t = 1; t < 64; t <<= 1) {
      s += __shfl_xor(s, t);
      c += __shfl_xor(c, t);
    }
    float f = s - 1.0f;
    float tnew = tau + f / c;               // c >= 1 while tau < tau*
    if (!(tnew > tau)) break;               // uniform across wave
    tau = tnew;
  }

  float4 oa, ob;
  oa.x = fmaxf(v0 - tau, 0.f);
  oa.y = fmaxf(v1 - tau, 0.f);
  oa.z = fmaxf(v2 - tau, 0.f);
  oa.w = fmaxf(v3 - tau, 0.f);
  ob.x = fmaxf(v4 - tau, 0.f);
  ob.y = fmaxf(v5 - tau, 0.f);
  ob.z = fmaxf(v6 - tau, 0.f);
  ob.w = fmaxf(v7 - tau, 0.f);
  ((float4*)zr)[lane] = oa;
  ((float4*)zr)[lane + 64] = ob;
}

extern "C" void kernel_launch(void* const* d_in, const int* in_sizes, int n_in,
                              void* d_out, int out_size, void* d_ws, size_t ws_size,
                              hipStream_t stream) {
  const float* x = (const float*)d_in[0];
  float* out = (float*)d_out;
  int nrows = out_size / N_COL;  // 16384

  tv_kernel<<<dim3((nrows + 63) / 64), dim3(64), 0, stream>>>(x, out, nrows);
  sparsemax_kernel<<<dim3((nrows + 3) / 4), dim3(256), 0, stream>>>(out, nrows);
}

// Round 4
// 370.155 us; speedup vs baseline: 1.1879x; 1.1879x over previous
//
#include <hip/hip_runtime.h>
#include <math.h>

#define N_COL 512
#define ALPHA 0.1f

// LDS layout: w[c][r] stored at sw[(c<<6) | ((r+c)&63)].
// - per-lane row reads (fixed r=lane, any per-lane c): banks (r+c)&31 -> random ~4-way worst
// - lockstep passes (fixed c-stride across lanes): banks cycle all 32 -> conflict-free
__device__ __forceinline__ int sidx(int c, int r) {
  return (c << 6) | ((r + c) & 63);
}

// ---------------------------------------------------------------------------
// Condat 1-D TV prox, one thread per row, 64 rows per block staged in LDS.
// Branchless flat state machine (exact port of reference's where-ladder) with
// 5-candidate LDS prefetch issued one iteration ahead: the next iteration's
// needed values w[k+1], w[km+1], w[kp+1] are always in
// {w[k+2], w[km+1], w[km+2], w[kp+1], w[kp+2]} (addresses known now).
// Markers (NaN-sentinel) go to global z, then forward-fill via LDS.
// ---------------------------------------------------------------------------
__global__ __launch_bounds__(64) void tv_kernel(const float* __restrict__ x,
                                                float* __restrict__ z) {
  __shared__ float sw[N_COL * 64];  // 128 KB
  const int n = N_COL;
  const float lam = ALPHA;
  const int lane = threadIdx.x;            // 0..63 = row within block
  const size_t rowBase = (size_t)blockIdx.x * 64;
  const float* gx = x + rowBase * n;
  float* gz = z + rowBase * n;
  float* gzr = gz + (size_t)lane * n;      // this lane's output row
  const float NANF = __uint_as_float(0x7fc00000u);

  // ---- Phase 1: stage rows into LDS (coalesced global, conflict-free LDS),
  //      init marker array to NaN (coalesced) ----
#pragma unroll 4
  for (int j = 0; j < n; ++j) {
    int flat = (j << 6) | lane;            // [0, 32768)
    int r = flat >> 9;
    int c = flat & (n - 1);
    sw[sidx(c, r)] = gx[flat];
    gz[flat] = NANF;
  }
  __syncthreads();

  // ---- Phase 2: state machine ----
  int k = 0, k0 = 0, km = 0, kp = 0;
  float w0 = sw[sidx(0, lane)];
  float vmin = w0 - lam, vmax = w0 + lam, umin = lam, umax = -lam;
  bool done = false;
  // prev-iteration flags (fake F for iteration 0: k_{-1}=-1, km=kp=0)
  bool Ap = false, Bp = false, Dp = false, Ep = false, g1p = false, g2p = false;
  float ck2 = sw[sidx(1, lane)];           // min(k+2)=1 under fake prev state
  float ckm1 = ck2, ckp1 = ck2;
  float ckm2 = sw[sidx(2, lane)];
  float ckp2 = ckm2;

  const int max_iter = 40 * n;
#pragma unroll 1
  for (int it = 0; it < max_iter; ++it) {
    // select this iteration's loaded values from prev candidates via prev flags
    float wk1 = (Ap | Dp) ? ckm2 : ((Bp | Ep) ? ckp2 : ck2);
    float wkm = (Ap | Dp) ? ckm2 : (Ep ? ckp2 : (g1p ? ck2 : ckm1));
    float wkp = (Bp | Ep) ? ckp2 : (Dp ? ckm2 : (g2p ? ck2 : ckp1));

    // issue next iteration's candidate loads (addresses from current state)
    int ik2  = min(k + 2, n - 1);
    int ikm1 = min(km + 1, n - 1);
    int ikm2 = min(km + 2, n - 1);
    int ikp1 = min(kp + 1, n - 1);
    int ikp2 = min(kp + 2, n - 1);
    ck2  = sw[sidx(ik2, lane)];
    ckm1 = sw[sidx(ikm1, lane)];
    ckm2 = sw[sidx(ikm2, lane)];
    ckp1 = sw[sidx(ikp1, lane)];
    ckp2 = sw[sidx(ikp2, lane)];

    // flat flag ladder (reference semantics), gated by !done
    bool act = !done;
    bool term = (k >= n - 1);
    float umin1 = umin + wk1 - vmin;
    float umax1 = umax + wk1 - vmax;
    bool negu = (umin < 0.f);
    bool A  = act & term & negu;
    bool Bb = act & term & !negu & (umax > 0.f);
    bool C  = act & term & !negu & !(umax > 0.f);
    bool D  = act & !term & (umin1 < -lam);
    bool E  = act & !term & !D & (umax1 > lam);
    bool F  = act & !term & !D & !E;

    float wk0 = (A | D) ? wkm : wkp;       // w[clip(k0n)], unused for C/F
    int k0n = (A | D) ? km + 1 : ((Bb | E) ? kp + 1 : k0);
    float fv = (A | D) ? vmin : ((Bb | E) ? vmax :
               vmin + umin * __builtin_amdgcn_rcpf((float)(k - k0 + 1)));
    bool flush = A | Bb | C | D | E;
    if (flush && (k0 < n)) gzr[k0] = fv;   // marker (scatter, off critical path)

    int kF = k + 1;
    bool g1 = F & (umin1 >= lam);
    bool g2 = F & (umax1 <= -lam);
    float rden = __builtin_amdgcn_rcpf((float)(kF - k0 + 1));

    int k_n  = F ? kF : ((A | Bb | D | E) ? k0n : k);
    int k0_n = (A | Bb | D | E) ? k0n : k0;
    int km_n = (A | D | E) ? k0n : (g1 ? kF : km);
    int kp_n = (Bb | D | E) ? k0n : (g2 ? kF : kp);
    float vmin_n = (A | D) ? wk0 : (E ? wk0 - 2.f * lam :
                   (g1 ? vmin + (umin1 - lam) * rden : vmin));
    float vmax_n = (Bb | E) ? wk0 : (D ? wk0 + 2.f * lam :
                   (g2 ? vmax + (umax1 + lam) * rden : vmax));
    float umin_n = (A | D | E) ? lam : (Bb ? wk0 - lam - vmin :
                   (F ? (g1 ? lam : umin1) : umin));
    float umax_n = (Bb | D | E) ? -lam : (A ? wk0 + lam - vmax :
                   (F ? (g2 ? -lam : umax1) : umax));

    k = k_n; k0 = k0_n; km = km_n; kp = kp_n;
    vmin = vmin_n; vmax = vmax_n; umin = umin_n; umax = umax_n;
    done = done | C;
    Ap = A; Bp = Bb; Dp = D; Ep = E; g1p = g1; g2p = g2;

    if (__ballot(!done) == 0ull) break;
  }
  __syncthreads();

  // ---- Phase 3: read markers back coalesced into LDS (transposed) ----
#pragma unroll 4
  for (int j = 0; j < n; ++j) {
    int flat = (j << 6) | lane;
    sw[sidx(flat & (n - 1), flat >> 9)] = gz[flat];
  }
  __syncthreads();

  // ---- Phase 4: per-thread forward fill (conflict-free lockstep) ----
  float cur = 0.f;
#pragma unroll 4
  for (int i = 0; i < n; ++i) {
    float v = sw[sidx(i, lane)];
    if (!(v != v)) cur = v;                // non-NaN -> new segment value
    sw[sidx(i, lane)] = cur;
  }
  __syncthreads();

  // ---- Phase 5: coalesced writeout ----
#pragma unroll 4
  for (int j = 0; j < n; ++j) {
    int flat = (j << 6) | lane;
    gz[flat] = sw[sidx(flat & (n - 1), flat >> 9)];
  }
}

// ---------------------------------------------------------------------------
// Sparsemax, one wave per row, 8 elements/lane in regs; Newton on
// f(tau) = sum(relu(z-tau)) - 1 (piecewise-linear, monotone from tau0=max-1).
// ---------------------------------------------------------------------------
__global__ __launch_bounds__(256) void sparsemax_kernel(float* __restrict__ z,
                                                        int nrows) {
  int wave = threadIdx.x >> 6;
  int lane = threadIdx.x & 63;
  int row = blockIdx.x * 4 + wave;
  if (row >= nrows) return;
  float* zr = z + (size_t)row * N_COL;

  float4 a = ((const float4*)zr)[lane];
  float4 b = ((const float4*)zr)[lane + 64];
  float v0 = a.x, v1 = a.y, v2 = a.z, v3 = a.w;
  float v4 = b.x, v5 = b.y, v6 = b.z, v7 = b.w;

  float m = fmaxf(fmaxf(fmaxf(v0, v1), fmaxf(v2, v3)),
                  fmaxf(fmaxf(v4, v5), fmaxf(v6, v7)));
#pragma unroll
  for (int s = 1; s < 64; s <<= 1) m = fmaxf(m, __shfl_xor(m, s));

  float tau = m - 1.0f;
  for (int iter = 0; iter < 64; ++iter) {
    float s = 0.f, c = 0.f;
    float d;
    d = v0 - tau; if (d > 0.f) { s += d; c += 1.f; }
    d = v1 - tau; if (d > 0.f) { s += d; c += 1.f; }
    d = v2 - tau; if (d > 0.f) { s += d; c += 1.f; }
    d = v3 - tau; if (d > 0.f) { s += d; c += 1.f; }
    d = v4 - tau; if (d > 0.f) { s += d; c += 1.f; }
    d = v5 - tau; if (d > 0.f) { s += d; c += 1.f; }
    d = v6 - tau; if (d > 0.f) { s += d; c += 1.f; }
    d = v7 - tau; if (d > 0.f) { s += d; c += 1.f; }
#pragma unroll
    for (int t = 1; t < 64; t <<= 1) {
      s += __shfl_xor(s, t);
      c += __shfl_xor(c, t);
    }
    float f = s - 1.0f;
    float tnew = tau + f / c;
    if (!(tnew > tau)) break;              // uniform across wave
    tau = tnew;
  }

  float4 oa, ob;
  oa.x = fmaxf(v0 - tau, 0.f);
  oa.y = fmaxf(v1 - tau, 0.f);
  oa.z = fmaxf(v2 - tau, 0.f);
  oa.w = fmaxf(v3 - tau, 0.f);
  ob.x = fmaxf(v4 - tau, 0.f);
  ob.y = fmaxf(v5 - tau, 0.f);
  ob.z = fmaxf(v6 - tau, 0.f);
  ob.w = fmaxf(v7 - tau, 0.f);
  ((float4*)zr)[lane] = oa;
  ((float4*)zr)[lane + 64] = ob;
}

extern "C" void kernel_launch(void* const* d_in, const int* in_sizes, int n_in,
                              void* d_out, int out_size, void* d_ws, size_t ws_size,
                              hipStream_t stream) {
  const float* x = (const float*)d_in[0];
  float* out = (float*)d_out;
  int nrows = out_size / N_COL;  // 16384

  tv_kernel<<<dim3(nrows / 64), dim3(64), 0, stream>>>(x, out);
  sparsemax_kernel<<<dim3((nrows + 3) / 4), dim3(256), 0, stream>>>(out, nrows);
}

// Round 5
// 359.100 us; speedup vs baseline: 1.2245x; 1.0308x over previous
//
#include <hip/hip_runtime.h>
#include <math.h>

#define N_COL 512
#define ALPHA 0.1f

// swizzled LDS index for w[c][r]: word (c<<6) | ((r+c)&63)
__device__ __forceinline__ int sidx(int c, int r) {
  return (c << 6) | ((r + c) & 63);
}

#define SW_WORDS (N_COL * 64)          // 32768 floats
#define MASK_OFF SW_WORDS              // 16 words x 64 rows bitmask
#define DUMMY_OFF (SW_WORDS + 16 * 64) // 64 per-lane dummy words
#define TOT_WORDS (DUMMY_OFF + 64)     // 33856 words = 135424 B

// ---------------------------------------------------------------------------
// Condat 1-D TV prox, one thread per row, 64 rows/block staged in swizzled LDS.
// Branchless flat state machine (exact port of reference where-ladder) with
// 5-candidate LDS prefetch one iteration ahead. Markers overwrite the dead
// prefix of w in LDS (k0 < all future reads); segment starts recorded in a
// register-buffered bitmask (k0 monotone -> write-only word flushes).
// ---------------------------------------------------------------------------
__global__ __launch_bounds__(64) void tv_kernel(const float* __restrict__ x,
                                                float* __restrict__ z) {
  __shared__ float sbuf[TOT_WORDS];
  unsigned* smask = (unsigned*)(sbuf + MASK_OFF);
  const int n = N_COL;
  const float lam = ALPHA;
  const int lane = threadIdx.x;            // row within block
  const size_t rowBase = (size_t)blockIdx.x * 64;
  const float* gx = x + rowBase * n;
  float* gz = z + rowBase * n;

  // ---- Phase 1: stage rows into LDS (float4 coalesced), zero mask ----
  {
    const float4* gx4 = (const float4*)gx;
#pragma unroll 2
    for (int j = 0; j < 128; ++j) {
      int flat4 = (j << 6) | lane;         // [0, 8192)
      float4 v = gx4[flat4];
      int flat = flat4 << 2;
      int r = flat >> 9;
      int c = flat & (n - 1);
      sbuf[sidx(c, r)] = v.x;
      sbuf[sidx(c + 1, r)] = v.y;
      sbuf[sidx(c + 2, r)] = v.z;
      sbuf[sidx(c + 3, r)] = v.w;
    }
#pragma unroll
    for (int j = 0; j < 16; ++j) smask[(j << 6) | lane] = 0u;
  }
  __syncthreads();

  // ---- Phase 2: state machine ----
  int k = 0, k0 = 0, km = 0, kp = 0;
  float w0 = sbuf[sidx(0, lane)];
  float vmin = w0 - lam, vmax = w0 + lam, umin = lam, umax = -lam;
  bool done = false;
  bool Ap = false, Bp = false, Dp = false, Ep = false, g1p = false, g2p = false;
  float ck2 = sbuf[sidx(1, lane)];
  float ckm1 = ck2, ckp1 = ck2;
  float ckm2 = sbuf[sidx(2, lane)];
  float ckp2 = ckm2;
  unsigned cw = 0u;                        // current mask word (reg-buffered)
  int cwi = 0;                             // its word index (monotone)

  const int max_iter = 40 * n;
#pragma unroll 1
  for (int it = 0; it < max_iter; ++it) {
    // select this iteration's values from prev candidates via prev flags
    float wk1 = (Ap | Dp) ? ckm2 : ((Bp | Ep) ? ckp2 : ck2);
    float wkm = (Ap | Dp) ? ckm2 : (Ep ? ckp2 : (g1p ? ck2 : ckm1));
    float wkp = (Bp | Ep) ? ckp2 : (Dp ? ckm2 : (g2p ? ck2 : ckp1));

    // issue next iteration's candidate loads
    int ik2  = min(k + 2, n - 1);
    int ikm1 = min(km + 1, n - 1);
    int ikm2 = min(km + 2, n - 1);
    int ikp1 = min(kp + 1, n - 1);
    int ikp2 = min(kp + 2, n - 1);
    ck2  = sbuf[sidx(ik2, lane)];
    ckm1 = sbuf[sidx(ikm1, lane)];
    ckm2 = sbuf[sidx(ikm2, lane)];
    ckp1 = sbuf[sidx(ikp1, lane)];
    ckp2 = sbuf[sidx(ikp2, lane)];

    // flat flag ladder (reference semantics), gated by !done
    bool act = !done;
    bool term = (k >= n - 1);
    float umin1 = umin + wk1 - vmin;
    float umax1 = umax + wk1 - vmax;
    bool negu = (umin < 0.f);
    bool A  = act & term & negu;
    bool Bb = act & term & !negu & (umax > 0.f);
    bool C  = act & term & !negu & !(umax > 0.f);
    bool D  = act & !term & (umin1 < -lam);
    bool E  = act & !term & !D & (umax1 > lam);
    bool F  = act & !term & !D & !E;

    float wk0 = (A | D) ? wkm : wkp;
    int k0n = (A | D) ? km + 1 : ((Bb | E) ? kp + 1 : k0);
    float fv = (A | D) ? vmin : ((Bb | E) ? vmax :
               vmin + umin * __builtin_amdgcn_rcpf((float)(k - k0 + 1)));
    bool flush = A | Bb | C | D | E;

    // branchless in-LDS marker + bitmask update
    sbuf[flush ? sidx(k0, lane) : (DUMMY_OFF + lane)] = fv;
    {
      int wi = k0 >> 5;
      bool cross = flush & (wi != cwi);
      ((unsigned*)sbuf)[cross ? (MASK_OFF + (cwi << 6) + lane)
                              : (DUMMY_OFF + lane)] = cw;
      cw = cross ? 0u : cw;
      cw |= flush ? (1u << (k0 & 31)) : 0u;
      cwi = cross ? wi : cwi;
    }

    int kF = k + 1;
    bool g1 = F & (umin1 >= lam);
    bool g2 = F & (umax1 <= -lam);
    float rden = __builtin_amdgcn_rcpf((float)(kF - k0 + 1));

    int k_n  = F ? kF : ((A | Bb | D | E) ? k0n : k);
    int k0_n = (A | Bb | D | E) ? k0n : k0;
    int km_n = (A | D | E) ? k0n : (g1 ? kF : km);
    int kp_n = (Bb | D | E) ? k0n : (g2 ? kF : kp);
    float vmin_n = (A | D) ? wk0 : (E ? wk0 - 2.f * lam :
                   (g1 ? vmin + (umin1 - lam) * rden : vmin));
    float vmax_n = (Bb | E) ? wk0 : (D ? wk0 + 2.f * lam :
                   (g2 ? vmax + (umax1 + lam) * rden : vmax));
    float umin_n = (A | D | E) ? lam : (Bb ? wk0 - lam - vmin :
                   (F ? (g1 ? lam : umin1) : umin));
    float umax_n = (Bb | D | E) ? -lam : (A ? wk0 + lam - vmax :
                   (F ? (g2 ? -lam : umax1) : umax));

    k = k_n; k0 = k0_n; km = km_n; kp = kp_n;
    vmin = vmin_n; vmax = vmax_n; umin = umin_n; umax = umax_n;
    done = done | C;
    Ap = A; Bp = Bb; Dp = D; Ep = E; g1p = g1; g2p = g2;

    if (((it & 7) == 7) && (__ballot(!done) == 0ull)) break;
  }
  // flush the last mask word
  smask[(cwi << 6) + lane] = cw;
  __syncthreads();

  // ---- Phase 3: per-thread forward fill using the bitmask ----
  {
    float cur = 0.f;
#pragma unroll 1
    for (int wi = 0; wi < 16; ++wi) {
      unsigned mw = smask[(wi << 6) + lane];
#pragma unroll
      for (int b = 0; b < 32; ++b) {
        int i = (wi << 5) + b;
        float v = sbuf[sidx(i, lane)];
        cur = ((mw >> b) & 1u) ? v : cur;
        sbuf[sidx(i, lane)] = cur;
      }
    }
  }
  __syncthreads();

  // ---- Phase 4: coalesced float4 writeout ----
  {
    float4* gz4 = (float4*)gz;
#pragma unroll 2
    for (int j = 0; j < 128; ++j) {
      int flat4 = (j << 6) | lane;
      int flat = flat4 << 2;
      int r = flat >> 9;
      int c = flat & (n - 1);
      float4 v;
      v.x = sbuf[sidx(c, r)];
      v.y = sbuf[sidx(c + 1, r)];
      v.z = sbuf[sidx(c + 2, r)];
      v.w = sbuf[sidx(c + 3, r)];
      gz4[flat4] = v;
    }
  }
}

// ---------------------------------------------------------------------------
// Sparsemax, one wave per row, 8 elements/lane in regs; Newton on
// f(tau) = sum(relu(z-tau)) - 1 (piecewise-linear, monotone from tau0=max-1).
// ---------------------------------------------------------------------------
__global__ __launch_bounds__(256) void sparsemax_kernel(float* __restrict__ z,
                                                        int nrows) {
  int wave = threadIdx.x >> 6;
  int lane = threadIdx.x & 63;
  int row = blockIdx.x * 4 + wave;
  if (row >= nrows) return;
  float* zr = z + (size_t)row * N_COL;

  float4 a = ((const float4*)zr)[lane];
  float4 b = ((const float4*)zr)[lane + 64];
  float v0 = a.x, v1 = a.y, v2 = a.z, v3 = a.w;
  float v4 = b.x, v5 = b.y, v6 = b.z, v7 = b.w;

  float m = fmaxf(fmaxf(fmaxf(v0, v1), fmaxf(v2, v3)),
                  fmaxf(fmaxf(v4, v5), fmaxf(v6, v7)));
#pragma unroll
  for (int s = 1; s < 64; s <<= 1) m = fmaxf(m, __shfl_xor(m, s));

  float tau = m - 1.0f;
  for (int iter = 0; iter < 64; ++iter) {
    float s = 0.f, c = 0.f;
    float d;
    d = v0 - tau; if (d > 0.f) { s += d; c += 1.f; }
    d = v1 - tau; if (d > 0.f) { s += d; c += 1.f; }
    d = v2 - tau; if (d > 0.f) { s += d; c += 1.f; }
    d = v3 - tau; if (d > 0.f) { s += d; c += 1.f; }
    d = v4 - tau; if (d > 0.f) { s += d; c += 1.f; }
    d = v5 - tau; if (d > 0.f) { s += d; c += 1.f; }
    d = v6 - tau; if (d > 0.f) { s += d; c += 1.f; }
    d = v7 - tau; if (d > 0.f) { s += d; c += 1.f; }
#pragma unroll
    for (int t = 1; t < 64; t <<= 1) {
      s += __shfl_xor(s, t);
      c += __shfl_xor(c, t);
    }
    float f = s - 1.0f;
    float tnew = tau + f / c;
    if (!(tnew > tau)) break;              // uniform across wave
    tau = tnew;
  }

  float4 oa, ob;
  oa.x = fmaxf(v0 - tau, 0.f);
  oa.y = fmaxf(v1 - tau, 0.f);
  oa.z = fmaxf(v2 - tau, 0.f);
  oa.w = fmaxf(v3 - tau, 0.f);
  ob.x = fmaxf(v4 - tau, 0.f);
  ob.y = fmaxf(v5 - tau, 0.f);
  ob.z = fmaxf(v6 - tau, 0.f);
  ob.w = fmaxf(v7 - tau, 0.f);
  ((float4*)zr)[lane] = oa;
  ((float4*)zr)[lane + 64] = ob;
}

extern "C" void kernel_launch(void* const* d_in, const int* in_sizes, int n_in,
                              void* d_out, int out_size, void* d_ws, size_t ws_size,
                              hipStream_t stream) {
  const float* x = (const float*)d_in[0];
  float* out = (float*)d_out;
  int nrows = out_size / N_COL;  // 16384

  tv_kernel<<<dim3(nrows / 64), dim3(64), 0, stream>>>(x, out);
  sparsemax_kernel<<<dim3((nrows + 3) / 4), dim3(256), 0, stream>>>(out, nrows);
}

// Round 6
// 209.286 us; speedup vs baseline: 2.1011x; 1.7158x over previous
//
#include <hip/hip_runtime.h>
#include <math.h>

#define N_COL 512
#define ALPHA 0.1f
#define NPAD 515                       // cols 512..514 hold w[511] (emulates clip)

// swizzled LDS index for w[c][r]: word (c<<6) | ((r+c)&63); bank = (r+c)&31
__device__ __forceinline__ int sidx(int c, int r) {
  return (c << 6) | ((r + c) & 63);
}

#define SW_WORDS (NPAD * 64)            // 32960 floats
#define MASK_OFF SW_WORDS               // 17 words x 64 rows bitmask
#define DUMMY_OFF (MASK_OFF + 17 * 64)  // 64 per-lane dummy words
#define TOT_WORDS (DUMMY_OFF + 64)      // 34112 words = 136448 B

// ---------------------------------------------------------------------------
// Condat 1-D TV prox, one thread per row, 64 rows/block staged in swizzled LDS.
// Two-loop split of the reference state machine:
//   loop1: scan cases D/E/F only (short ladder), lanes freeze at k>=n-1
//   loop2: one terminal A/B/C step; bounced lanes re-enter loop1
// 5-candidate prefetch one iteration ahead in loop1; markers overwrite the
// dead prefix of w (k0 strictly increases; all reads > k0); segment starts in
// a register-buffered bitmask stored unconditionally each iteration.
// All of k,k0,km,kp clipped to [0,512]; LDS cols 512..514 = w[511].
// ---------------------------------------------------------------------------
__global__ __launch_bounds__(64) void tv_kernel(const float* __restrict__ x,
                                                float* __restrict__ z) {
  __shared__ float sbuf[TOT_WORDS];
  unsigned* smask = (unsigned*)(sbuf + MASK_OFF);
  const int n = N_COL;                   // 512
  const float lam = ALPHA;
  const int lane = threadIdx.x;
  const size_t rowBase = (size_t)blockIdx.x * 64;
  const float* gx = x + rowBase * n;
  float* gz = z + rowBase * n;

  // ---- Phase 1: stage rows into LDS (float4 coalesced), pad, zero mask ----
  float wlast = gx[(size_t)lane * n + (n - 1)];   // this lane's row tail
  {
    const float4* gx4 = (const float4*)gx;
#pragma unroll 2
    for (int j = 0; j < 128; ++j) {
      int flat4 = (j << 6) | lane;
      float4 v = gx4[flat4];
      int flat = flat4 << 2;
      int r = flat >> 9;
      int c = flat & (n - 1);
      sbuf[sidx(c, r)] = v.x;
      sbuf[sidx(c + 1, r)] = v.y;
      sbuf[sidx(c + 2, r)] = v.z;
      sbuf[sidx(c + 3, r)] = v.w;
    }
    sbuf[sidx(512, lane)] = wlast;
    sbuf[sidx(513, lane)] = wlast;
    sbuf[sidx(514, lane)] = wlast;
#pragma unroll
    for (int j = 0; j < 17; ++j) smask[(j << 6) | lane] = 0u;
  }
  __syncthreads();

  // ---- Phase 2: two-loop state machine ----
  int k = 0, k0 = 0, km = 0, kp = 0;
  float w0 = sbuf[sidx(0, lane)];
  float vmin = w0 - lam, vmax = w0 + lam, umin = lam, umax = -lam;
  bool done = false;
  unsigned cw = 0u;
  int cwi = 0;
  int budget = 40 * n;

  while (budget > 0 && __ballot(!done) != 0ull) {
    // candidate reload for loop1 entry (prev flags cleared -> direct mapping)
    float ck2  = sbuf[sidx(k + 1, lane)];
    float ckm1 = sbuf[sidx(km + 1, lane)];
    float ckm2 = sbuf[sidx(km + 2, lane)];
    float ckp1 = sbuf[sidx(kp + 1, lane)];
    float ckp2 = sbuf[sidx(kp + 2, lane)];
    bool Dp = false, Ep = false, g1p = false, g2p = false;

    // ---- loop1: scan (D/E/F) until all lanes terminal or done ----
    while (budget > 0) {
      if (__ballot(k < n - 1) == 0ull) break;
      budget -= 8;
#pragma unroll
      for (int u = 0; u < 8; ++u) {
        float wk1 = Dp ? ckm2 : (Ep ? ckp2 : ck2);
        float wkm = Dp ? ckm2 : (Ep ? ckp2 : (g1p ? ck2 : ckm1));
        float wkp = Ep ? ckp2 : (Dp ? ckm2 : (g2p ? ck2 : ckp1));

        ck2  = sbuf[sidx(k + 2, lane)];      // k  <= 512 -> col <= 514
        ckm1 = sbuf[sidx(km + 1, lane)];     // km <= 512 -> col <= 514
        ckm2 = sbuf[sidx(km + 2, lane)];
        ckp1 = sbuf[sidx(kp + 1, lane)];
        ckp2 = sbuf[sidx(kp + 2, lane)];

        bool act = (k < n - 1);              // done lanes have k = n-1
        float umin1 = umin + wk1 - vmin;
        float umax1 = umax + wk1 - vmax;
        bool D = act & (umin1 < -lam);
        bool E = act & !D & (umax1 > lam);
        bool F = act & !D & !E;
        bool flush = D | E;

        int k0n = min(D ? km + 1 : kp + 1, n);
        float fv = D ? vmin : vmax;
        float wk0 = D ? wkm : wkp;

        sbuf[flush ? sidx(k0, lane) : (DUMMY_OFF + lane)] = fv;  // k0<512 here
        int wi = flush ? (k0 >> 5) : cwi;
        cw = (wi != cwi) ? 0u : cw;
        cwi = wi;
        cw |= flush ? (1u << (k0 & 31)) : 0u;
        smask[(cwi << 6) + lane] = cw;

        int kF = k + 1;
        bool g1 = F & (umin1 >= lam);
        bool g2 = F & (umax1 <= -lam);
        float rden = __builtin_amdgcn_rcpf((float)(kF - k0 + 1));

        k  = F ? kF : (flush ? k0n : k);
        k0 = flush ? k0n : k0;
        km = flush ? k0n : (g1 ? kF : km);
        kp = flush ? k0n : (g2 ? kF : kp);
        vmin = D ? wk0 : (E ? wk0 - 2.f * lam :
               (g1 ? vmin + (umin1 - lam) * rden : vmin));
        vmax = E ? wk0 : (D ? wk0 + 2.f * lam :
               (g2 ? vmax + (umax1 + lam) * rden : vmax));
        umin = flush ? lam  : (F ? (g1 ? lam : umin1) : umin);
        umax = flush ? -lam : (F ? (g2 ? -lam : umax1) : umax);
        Dp = D; Ep = E; g1p = g1; g2p = g2;
      }
    }

    // ---- loop2: one terminal step (A/B/C) for lanes with k >= n-1 ----
    {
      bool act = (k >= n - 1) & !done;
      bool A  = act & (umin < 0.f);
      bool Bb = act & !A & (umax > 0.f);
      bool C  = act & !A & !Bb;
      int k0n = min(A ? km + 1 : kp + 1, n);
      float wk0 = sbuf[sidx(min(k0n, n - 1), lane)];   // reference clip
      float fv = A ? vmin : (Bb ? vmax :
                 vmin + umin * __builtin_amdgcn_rcpf((float)(k - k0 + 1)));
      bool valid = (A | Bb | C) & (k0 < n);            // k0 == n -> dropped
      sbuf[valid ? sidx(k0, lane) : (DUMMY_OFF + lane)] = fv;
      int wi = valid ? (k0 >> 5) : cwi;
      cw = (wi != cwi) ? 0u : cw;
      cwi = wi;
      cw |= valid ? (1u << (k0 & 31)) : 0u;
      smask[(cwi << 6) + lane] = cw;

      float umax_n = Bb ? -lam : (A ? wk0 + lam - vmax : umax);  // old vmax
      float umin_n = A ? lam  : (Bb ? wk0 - lam - vmin : umin);  // old vmin
      vmin = A ? wk0 : vmin;
      vmax = Bb ? wk0 : vmax;
      umin = umin_n; umax = umax_n;
      k  = (A | Bb) ? k0n : k;
      k0 = (A | Bb) ? k0n : k0;
      km = A ? k0n : km;
      kp = Bb ? k0n : kp;
      done = done | C;
      budget -= 1;
    }
  }
  __syncthreads();

  // ---- Phase 3: per-thread forward fill using the bitmask ----
  {
    float cur = 0.f;
#pragma unroll 1
    for (int wi = 0; wi < 16; ++wi) {
      unsigned mw = smask[(wi << 6) + lane];
#pragma unroll
      for (int b = 0; b < 32; ++b) {
        int i = (wi << 5) + b;
        float v = sbuf[sidx(i, lane)];
        cur = ((mw >> b) & 1u) ? v : cur;
        sbuf[sidx(i, lane)] = cur;
      }
    }
  }
  __syncthreads();

  // ---- Phase 4: coalesced float4 writeout ----
  {
    float4* gz4 = (float4*)gz;
#pragma unroll 2
    for (int j = 0; j < 128; ++j) {
      int flat4 = (j << 6) | lane;
      int flat = flat4 << 2;
      int r = flat >> 9;
      int c = flat & (n - 1);
      float4 v;
      v.x = sbuf[sidx(c, r)];
      v.y = sbuf[sidx(c + 1, r)];
      v.z = sbuf[sidx(c + 2, r)];
      v.w = sbuf[sidx(c + 3, r)];
      gz4[flat4] = v;
    }
  }
}

// ---------------------------------------------------------------------------
// Sparsemax, one wave per row, 8 elements/lane in regs; Newton on
// f(tau) = sum(relu(z-tau)) - 1 (piecewise-linear, monotone from tau0=max-1).
// ---------------------------------------------------------------------------
__global__ __launch_bounds__(256) void sparsemax_kernel(float* __restrict__ z,
                                                        int nrows) {
  int wave = threadIdx.x >> 6;
  int lane = threadIdx.x & 63;
  int row = blockIdx.x * 4 + wave;
  if (row >= nrows) return;
  float* zr = z + (size_t)row * N_COL;

  float4 a = ((const float4*)zr)[lane];
  float4 b = ((const float4*)zr)[lane + 64];
  float v0 = a.x, v1 = a.y, v2 = a.z, v3 = a.w;
  float v4 = b.x, v5 = b.y, v6 = b.z, v7 = b.w;

  float m = fmaxf(fmaxf(fmaxf(v0, v1), fmaxf(v2, v3)),
                  fmaxf(fmaxf(v4, v5), fmaxf(v6, v7)));
#pragma unroll
  for (int s = 1; s < 64; s <<= 1) m = fmaxf(m, __shfl_xor(m, s));

  float tau = m - 1.0f;
  for (int iter = 0; iter < 64; ++iter) {
    float s = 0.f, c = 0.f;
    float d;
    d = v0 - tau; if (d > 0.f) { s += d; c += 1.f; }
    d = v1 - tau; if (d > 0.f) { s += d; c += 1.f; }
    d = v2 - tau; if (d > 0.f) { s += d; c += 1.f; }
    d = v3 - tau; if (d > 0.f) { s += d; c += 1.f; }
    d = v4 - tau; if (d > 0.f) { s += d; c += 1.f; }
    d = v5 - tau; if (d > 0.f) { s += d; c += 1.f; }
    d = v6 - tau; if (d > 0.f) { s += d; c += 1.f; }
    d = v7 - tau; if (d > 0.f) { s += d; c += 1.f; }
#pragma unroll
    for (int t = 1; t < 64; t <<= 1) {
      s += __shfl_xor(s, t);
      c += __shfl_xor(c, t);
    }
    float f = s - 1.0f;
    float tnew = tau + f / c;
    if (!(tnew > tau)) break;              // uniform across wave
    tau = tnew;
  }

  float4 oa, ob;
  oa.x = fmaxf(v0 - tau, 0.f);
  oa.y = fmaxf(v1 - tau, 0.f);
  oa.z = fmaxf(v2 - tau, 0.f);
  oa.w = fmaxf(v3 - tau, 0.f);
  ob.x = fmaxf(v4 - tau, 0.f);
  ob.y = fmaxf(v5 - tau, 0.f);
  ob.z = fmaxf(v6 - tau, 0.f);
  ob.w = fmaxf(v7 - tau, 0.f);
  ((float4*)zr)[lane] = oa;
  ((float4*)zr)[lane + 64] = ob;
}

extern "C" void kernel_launch(void* const* d_in, const int* in_sizes, int n_in,
                              void* d_out, int out_size, void* d_ws, size_t ws_size,
                              hipStream_t stream) {
  const float* x = (const float*)d_in[0];
  float* out = (float*)d_out;
  int nrows = out_size / N_COL;  // 16384

  tv_kernel<<<dim3(nrows / 64), dim3(64), 0, stream>>>(x, out);
  sparsemax_kernel<<<dim3((nrows + 3) / 4), dim3(256), 0, stream>>>(out, nrows);
}